// Round 5
// baseline (34049.155 us; speedup 1.0000x reference)
//
#include <hip/hip_runtime.h>

#define T_STEPS 65536
#define NIN 99
#define HID 64
#define G4 256   // 4*HID gates
#define TS 128   // timesteps per block in the projection kernel

typedef _Float16 half2v __attribute__((ext_vector_type(2)));

__device__ __forceinline__ float frcp(float x) { return __builtin_amdgcn_rcpf(x); }
__device__ __forceinline__ float fexp2(float x) { return __builtin_amdgcn_exp2f(x); }

#define LOG2E 1.4426950408889634f

__device__ __forceinline__ float sigmoid_f(float x) { return frcp(1.0f + fexp2(x * -LOG2E)); }
__device__ __forceinline__ float tanh_f(float x) {
    float ax = fabsf(x);
    float e  = fexp2(ax * (2.0f * LOG2E));     // inf for large ax fine: rcp(inf)=0
    float r  = 1.0f - 2.0f * frcp(e + 1.0f);
    return copysignf(r, x);
}

// pack two f32 into half2 (v_cvt_pkrtz_f16_f32, 1 instr)
__device__ __forceinline__ half2v pk16(float a, float b) {
#if __has_builtin(__builtin_amdgcn_cvt_pkrtz)
    return __builtin_bit_cast(half2v, __builtin_amdgcn_cvt_pkrtz(a, b));
#else
    half2v r; r.x = (_Float16)a; r.y = (_Float16)b; return r;
#endif
}
// v_dot2_f32_f16: 2 MACs per instr, f32 accumulate.
__device__ __forceinline__ float fdot2f(half2v a, half2v b, float c) {
#if __has_builtin(__builtin_amdgcn_fdot2)
    return __builtin_amdgcn_fdot2(a, b, c, false);
#else
    return fmaf((float)a.x, (float)b.x, fmaf((float)a.y, (float)b.y, c));
#endif
}

// ---------------- Kernel 1: xz2[t][unit][4] = gates (i,f,g,o) of unit ----------------
__global__ __launch_bounds__(256, 1) void xz_kernel(
    const float* __restrict__ x, const float* __restrict__ W_ih,
    const float* __restrict__ b_ih, const float* __restrict__ b_hh,
    float* __restrict__ xz2) {
    __shared__ __align__(16) float xs[TS * 100];   // padded rows: 400 B stride
    const int g  = threadIdx.x;                    // gate row 0..255
    const int t0 = blockIdx.x * TS;
    const int unit = g & 63, d = g >> 6;           // transposed write position

    for (int i = g; i < TS * NIN; i += 256) {
        int tl = i / NIN;
        int j  = i - tl * NIN;
        xs[tl * 100 + j] = x[(size_t)t0 * NIN + i];
    }

    float w[NIN];
#pragma unroll
    for (int j = 0; j < NIN; ++j) w[j] = W_ih[g * NIN + j];
    const float bias = b_ih[g] + b_hh[g];
    __syncthreads();

    for (int tl = 0; tl < TS; ++tl) {
        const float* xr = &xs[tl * 100];
        float a0 = bias, a1 = 0.f, a2 = 0.f, a3 = 0.f;
#pragma unroll
        for (int j4 = 0; j4 < 24; ++j4) {
            float4 xv = *(const float4*)(xr + 4 * j4);
            a0 = fmaf(w[4 * j4 + 0], xv.x, a0);
            a1 = fmaf(w[4 * j4 + 1], xv.y, a1);
            a2 = fmaf(w[4 * j4 + 2], xv.z, a2);
            a3 = fmaf(w[4 * j4 + 3], xv.w, a3);
        }
        a0 = fmaf(w[96], xr[96], a0);
        a1 = fmaf(w[97], xr[97], a1);
        a2 = fmaf(w[98], xr[98], a2);
        xz2[(size_t)(t0 + tl) * G4 + unit * 4 + d] = (a0 + a1) + (a2 + a3);
    }
}

// ---------------- Kernel 2: SINGLE-WAVE LSTM, weights in NAMED registers ----------
// R4 post-mortem: VGPR_Count=88 proved the weight arrays never became resident
// (asm-pin-in-loop -> AGPR/scratch parking; ~128 reload ops/step). Fix: 128
// named int variables (macro-expanded, compile-time everything, no pins).
// Per step: 1 mov_dpp + 1 cvt_pkrtz + 32 readlane + 128 v_dot2_f32_f16
// (8 independent accumulator chains) + activations ~ 200 instr.
__global__ __launch_bounds__(64, 1) __attribute__((amdgpu_waves_per_eu(1)))
void lstm_kernel(
    const float* __restrict__ xz2, const float* __restrict__ W_hh,
    const float* __restrict__ W1, const float* __restrict__ W2,
    const float* __restrict__ b2, float* __restrict__ out) {
    __shared__ float hfin[HID];
    __shared__ float hbuf[32];
    const int l = threadIdx.x;     // 0..63, unit index

    // W_hh rows l (i), 64+l (f), 128+l (g), 192+l (o); packed half2 pairs.
    const float* Wb = W_hh + l * HID;
#define PKW(OFF, J) __builtin_bit_cast(int, pk16(Wb[(OFF) + 2*(J)], Wb[(OFF) + 2*(J) + 1]))
#define DECLG(P, OFF)                                                           \
    const int P##0  = PKW(OFF, 0),  P##1  = PKW(OFF, 1),  P##2  = PKW(OFF, 2),  \
              P##3  = PKW(OFF, 3),  P##4  = PKW(OFF, 4),  P##5  = PKW(OFF, 5),  \
              P##6  = PKW(OFF, 6),  P##7  = PKW(OFF, 7),  P##8  = PKW(OFF, 8),  \
              P##9  = PKW(OFF, 9),  P##10 = PKW(OFF,10),  P##11 = PKW(OFF,11),  \
              P##12 = PKW(OFF,12),  P##13 = PKW(OFF,13),  P##14 = PKW(OFF,14),  \
              P##15 = PKW(OFF,15),  P##16 = PKW(OFF,16),  P##17 = PKW(OFF,17),  \
              P##18 = PKW(OFF,18),  P##19 = PKW(OFF,19),  P##20 = PKW(OFF,20),  \
              P##21 = PKW(OFF,21),  P##22 = PKW(OFF,22),  P##23 = PKW(OFF,23),  \
              P##24 = PKW(OFF,24),  P##25 = PKW(OFF,25),  P##26 = PKW(OFF,26),  \
              P##27 = PKW(OFF,27),  P##28 = PKW(OFF,28),  P##29 = PKW(OFF,29),  \
              P##30 = PKW(OFF,30),  P##31 = PKW(OFF,31);
    DECLG(wi, 0)
    DECLG(wf, 4096)
    DECLG(wg, 8192)
    DECLG(wo, 12288)
#undef DECLG
#undef PKW

    float h = 0.0f, c = 0.0f;      // lane l: h[l], c[l]

    // xz: unit l's 4 gates contiguous -> one dwordx4 per step. 4-step blocks,
    // named prefetch registers (no arrays).
    const float* zi = xz2 + 4 * l;
#define ZLD(T) (*(const float4*)(zi + (size_t)(T) * G4))
    float4 z0 = ZLD(0), z1 = ZLD(1), z2 = ZLD(2), z3 = ZLD(3);
    float4 n0, n1, n2, n3;

    // one LSTM step: z = xz float4; updates h, c
#define DOTJ(J)                                                                 \
    {   half2v hp = __builtin_bit_cast(half2v,                                  \
            __builtin_amdgcn_readlane(hpi, 2 * (J)));                           \
        if ((J) & 1) {                                                          \
            ai1 = fdot2f(__builtin_bit_cast(half2v, wi##J), hp, ai1);           \
            af1 = fdot2f(__builtin_bit_cast(half2v, wf##J), hp, af1);           \
            ag1 = fdot2f(__builtin_bit_cast(half2v, wg##J), hp, ag1);           \
            ao1 = fdot2f(__builtin_bit_cast(half2v, wo##J), hp, ao1);           \
        } else {                                                                \
            ai0 = fdot2f(__builtin_bit_cast(half2v, wi##J), hp, ai0);           \
            af0 = fdot2f(__builtin_bit_cast(half2v, wf##J), hp, af0);           \
            ag0 = fdot2f(__builtin_bit_cast(half2v, wg##J), hp, ag0);           \
            ao0 = fdot2f(__builtin_bit_cast(half2v, wo##J), hp, ao0);           \
        } }
#define STEP(Z)                                                                 \
    {   float ai0 = Z.x, af0 = Z.y, ag0 = Z.z, ao0 = Z.w;                       \
        float ai1 = 0.f, af1 = 0.f, ag1 = 0.f, ao1 = 0.f;                       \
        float hn = __int_as_float(__builtin_amdgcn_mov_dpp(                     \
            __float_as_int(h), 0xB1 /*quad_perm [1,0,3,2]*/, 0xF, 0xF, true));  \
        const int hpi = __builtin_bit_cast(int, pk16(h, hn));                   \
        DOTJ(0)  DOTJ(1)  DOTJ(2)  DOTJ(3)  DOTJ(4)  DOTJ(5)  DOTJ(6)  DOTJ(7)  \
        DOTJ(8)  DOTJ(9)  DOTJ(10) DOTJ(11) DOTJ(12) DOTJ(13) DOTJ(14) DOTJ(15) \
        DOTJ(16) DOTJ(17) DOTJ(18) DOTJ(19) DOTJ(20) DOTJ(21) DOTJ(22) DOTJ(23) \
        DOTJ(24) DOTJ(25) DOTJ(26) DOTJ(27) DOTJ(28) DOTJ(29) DOTJ(30) DOTJ(31) \
        float ig = sigmoid_f(ai0 + ai1);                                        \
        float fg = sigmoid_f(af0 + af1);                                        \
        float gg = tanh_f(ag0 + ag1);                                           \
        float og = sigmoid_f(ao0 + ao1);                                        \
        c = fmaf(fg, c, ig * gg);                                               \
        h = og * tanh_f(c); }

    for (int tb = 0; tb < T_STEPS; tb += 4) {
        if (tb + 4 < T_STEPS) {
            n0 = ZLD(tb + 4); n1 = ZLD(tb + 5); n2 = ZLD(tb + 6); n3 = ZLD(tb + 7);
        }
        STEP(z0) STEP(z1) STEP(z2) STEP(z3)
        z0 = n0; z1 = n1; z2 = n2; z3 = n3;
    }
#undef STEP
#undef DOTJ
#undef ZLD

    // head: out = W2 @ relu(W1 @ relu(h_T)) + b2  (single wave)
    hfin[l] = h;
    __syncthreads();
    if (l < 32) {
        float s = 0.0f;
#pragma unroll
        for (int j = 0; j < HID; ++j) s += W1[l * HID + j] * fmaxf(hfin[j], 0.0f);
        hbuf[l] = fmaxf(s, 0.0f);
    }
    __syncthreads();
    if (l < 3) {
        float s = b2[l];
#pragma unroll
        for (int j = 0; j < 32; ++j) s += W2[l * 32 + j] * hbuf[j];
        out[l] = s;
    }
}

extern "C" void kernel_launch(void* const* d_in, const int* in_sizes, int n_in,
                              void* d_out, int out_size, void* d_ws, size_t ws_size,
                              hipStream_t stream) {
    const float* x   = (const float*)d_in[0];
    const float* Wih = (const float*)d_in[1];
    const float* Whh = (const float*)d_in[2];
    const float* bih = (const float*)d_in[3];
    const float* bhh = (const float*)d_in[4];
    const float* W1  = (const float*)d_in[5];
    const float* W2  = (const float*)d_in[6];
    const float* b2  = (const float*)d_in[7];
    float* out = (float*)d_out;
    float* xz2 = (float*)d_ws;   // T_STEPS * 256 floats = 64 MB (transposed layout)

    xz_kernel<<<T_STEPS / TS, 256, 0, stream>>>(x, Wih, bih, bhh, xz2);
    lstm_kernel<<<1, 64, 0, stream>>>(xz2, Whh, W1, W2, b2, out);
}

// Round 6
// 34043.005 us; speedup vs baseline: 1.0002x; 1.0002x over previous
//
#include <hip/hip_runtime.h>

#define T_STEPS 65536
#define NIN 99
#define HID 64
#define G4 256   // 4*HID gates
#define TS 128   // timesteps per block in the projection kernel

typedef _Float16 half2v __attribute__((ext_vector_type(2)));

__device__ __forceinline__ float frcp(float x) { return __builtin_amdgcn_rcpf(x); }
__device__ __forceinline__ float fexp2(float x) { return __builtin_amdgcn_exp2f(x); }

#define LOG2E 1.4426950408889634f

__device__ __forceinline__ float sigmoid_f(float x) { return frcp(1.0f + fexp2(x * -LOG2E)); }
__device__ __forceinline__ float tanh_f(float x) {
    float ax = fabsf(x);
    float e  = fexp2(ax * (2.0f * LOG2E));     // inf for large ax fine: rcp(inf)=0
    float r  = 1.0f - 2.0f * frcp(e + 1.0f);
    return copysignf(r, x);
}

// pack two f32 into half2 (v_cvt_pkrtz_f16_f32, 1 instr)
__device__ __forceinline__ half2v pk16(float a, float b) {
#if __has_builtin(__builtin_amdgcn_cvt_pkrtz)
    return __builtin_bit_cast(half2v, __builtin_amdgcn_cvt_pkrtz(a, b));
#else
    half2v r; r.x = (_Float16)a; r.y = (_Float16)b; return r;
#endif
}
// v_dot2_f32_f16: 2 MACs per instr, f32 accumulate.
__device__ __forceinline__ float fdot2f(half2v a, half2v b, float c) {
#if __has_builtin(__builtin_amdgcn_fdot2)
    return __builtin_amdgcn_fdot2(a, b, c, false);
#else
    return fmaf((float)a.x, (float)b.x, fmaf((float)a.y, (float)b.y, c));
#endif
}

// ---------------- Kernel 1: xz2[t][unit][4] = gates (i,f,g,o) of unit ----------------
__global__ __launch_bounds__(256, 1) void xz_kernel(
    const float* __restrict__ x, const float* __restrict__ W_ih,
    const float* __restrict__ b_ih, const float* __restrict__ b_hh,
    float* __restrict__ xz2) {
    __shared__ __align__(16) float xs[TS * 100];   // padded rows: 400 B stride
    const int g  = threadIdx.x;                    // gate row 0..255
    const int t0 = blockIdx.x * TS;
    const int unit = g & 63, d = g >> 6;           // transposed write position

    for (int i = g; i < TS * NIN; i += 256) {
        int tl = i / NIN;
        int j  = i - tl * NIN;
        xs[tl * 100 + j] = x[(size_t)t0 * NIN + i];
    }

    float w[NIN];
#pragma unroll
    for (int j = 0; j < NIN; ++j) w[j] = W_ih[g * NIN + j];
    const float bias = b_ih[g] + b_hh[g];
    __syncthreads();

    for (int tl = 0; tl < TS; ++tl) {
        const float* xr = &xs[tl * 100];
        float a0 = bias, a1 = 0.f, a2 = 0.f, a3 = 0.f;
#pragma unroll
        for (int j4 = 0; j4 < 24; ++j4) {
            float4 xv = *(const float4*)(xr + 4 * j4);
            a0 = fmaf(w[4 * j4 + 0], xv.x, a0);
            a1 = fmaf(w[4 * j4 + 1], xv.y, a1);
            a2 = fmaf(w[4 * j4 + 2], xv.z, a2);
            a3 = fmaf(w[4 * j4 + 3], xv.w, a3);
        }
        a0 = fmaf(w[96], xr[96], a0);
        a1 = fmaf(w[97], xr[97], a1);
        a2 = fmaf(w[98], xr[98], a2);
        xz2[(size_t)(t0 + tl) * G4 + unit * 4 + d] = (a0 + a1) + (a2 + a3);
    }
}

// ---------------- Kernel 2: SINGLE-WAVE LSTM, occupancy target PINNED to 1 ----------
// R5 post-mortem: VGPR counts across rounds (40/80/88/116) all sit under the
// 4- or 8-wave-per-EU register budgets (128/64) -> the scheduler's remat stage
// targets occupancy 4 and sinks ~100 weight loads into the step loop
// (~420 instr/step measured vs ~200 budget). waves_per_eu(1) only sets the
// MINIMUM. waves_per_eu(1,1) pins min=max=1 -> 512-reg budget -> no remat;
// all 128 packed-weight ints stay resident. Only one wave runs, so max=1 free.
__global__ __launch_bounds__(64) __attribute__((amdgpu_waves_per_eu(1, 1)))
void lstm_kernel(
    const float* __restrict__ xz2, const float* __restrict__ W_hh,
    const float* __restrict__ W1, const float* __restrict__ W2,
    const float* __restrict__ b2, float* __restrict__ out) {
    __shared__ float hfin[HID];
    __shared__ float hbuf[32];
    const int l = threadIdx.x;     // 0..63, unit index

    // W_hh rows l (i), 64+l (f), 128+l (g), 192+l (o); packed half2 pairs.
    const float* Wb = W_hh + l * HID;
#define PKW(OFF, J) __builtin_bit_cast(int, pk16(Wb[(OFF) + 2*(J)], Wb[(OFF) + 2*(J) + 1]))
#define DECLG(P, OFF)                                                           \
    const int P##0  = PKW(OFF, 0),  P##1  = PKW(OFF, 1),  P##2  = PKW(OFF, 2),  \
              P##3  = PKW(OFF, 3),  P##4  = PKW(OFF, 4),  P##5  = PKW(OFF, 5),  \
              P##6  = PKW(OFF, 6),  P##7  = PKW(OFF, 7),  P##8  = PKW(OFF, 8),  \
              P##9  = PKW(OFF, 9),  P##10 = PKW(OFF,10),  P##11 = PKW(OFF,11),  \
              P##12 = PKW(OFF,12),  P##13 = PKW(OFF,13),  P##14 = PKW(OFF,14),  \
              P##15 = PKW(OFF,15),  P##16 = PKW(OFF,16),  P##17 = PKW(OFF,17),  \
              P##18 = PKW(OFF,18),  P##19 = PKW(OFF,19),  P##20 = PKW(OFF,20),  \
              P##21 = PKW(OFF,21),  P##22 = PKW(OFF,22),  P##23 = PKW(OFF,23),  \
              P##24 = PKW(OFF,24),  P##25 = PKW(OFF,25),  P##26 = PKW(OFF,26),  \
              P##27 = PKW(OFF,27),  P##28 = PKW(OFF,28),  P##29 = PKW(OFF,29),  \
              P##30 = PKW(OFF,30),  P##31 = PKW(OFF,31);
    DECLG(wi, 0)
    DECLG(wf, 4096)
    DECLG(wg, 8192)
    DECLG(wo, 12288)
#undef DECLG
#undef PKW

    float h = 0.0f, c = 0.0f;      // lane l: h[l], c[l]

    // xz: unit l's 4 gates contiguous -> one dwordx4 per step. 4-step blocks,
    // named prefetch registers (no arrays).
    const float* zi = xz2 + 4 * l;
#define ZLD(T) (*(const float4*)(zi + (size_t)(T) * G4))
    float4 z0 = ZLD(0), z1 = ZLD(1), z2 = ZLD(2), z3 = ZLD(3);
    float4 n0, n1, n2, n3;

    // one LSTM step: z = xz float4; updates h, c
#define DOTJ(J)                                                                 \
    {   half2v hp = __builtin_bit_cast(half2v,                                  \
            __builtin_amdgcn_readlane(hpi, 2 * (J)));                           \
        if ((J) & 1) {                                                          \
            ai1 = fdot2f(__builtin_bit_cast(half2v, wi##J), hp, ai1);           \
            af1 = fdot2f(__builtin_bit_cast(half2v, wf##J), hp, af1);           \
            ag1 = fdot2f(__builtin_bit_cast(half2v, wg##J), hp, ag1);           \
            ao1 = fdot2f(__builtin_bit_cast(half2v, wo##J), hp, ao1);           \
        } else {                                                                \
            ai0 = fdot2f(__builtin_bit_cast(half2v, wi##J), hp, ai0);           \
            af0 = fdot2f(__builtin_bit_cast(half2v, wf##J), hp, af0);           \
            ag0 = fdot2f(__builtin_bit_cast(half2v, wg##J), hp, ag0);           \
            ao0 = fdot2f(__builtin_bit_cast(half2v, wo##J), hp, ao0);           \
        } }
#define STEP(Z)                                                                 \
    {   float ai0 = Z.x, af0 = Z.y, ag0 = Z.z, ao0 = Z.w;                       \
        float ai1 = 0.f, af1 = 0.f, ag1 = 0.f, ao1 = 0.f;                       \
        float hn = __int_as_float(__builtin_amdgcn_mov_dpp(                     \
            __float_as_int(h), 0xB1 /*quad_perm [1,0,3,2]*/, 0xF, 0xF, true));  \
        const int hpi = __builtin_bit_cast(int, pk16(h, hn));                   \
        DOTJ(0)  DOTJ(1)  DOTJ(2)  DOTJ(3)  DOTJ(4)  DOTJ(5)  DOTJ(6)  DOTJ(7)  \
        DOTJ(8)  DOTJ(9)  DOTJ(10) DOTJ(11) DOTJ(12) DOTJ(13) DOTJ(14) DOTJ(15) \
        DOTJ(16) DOTJ(17) DOTJ(18) DOTJ(19) DOTJ(20) DOTJ(21) DOTJ(22) DOTJ(23) \
        DOTJ(24) DOTJ(25) DOTJ(26) DOTJ(27) DOTJ(28) DOTJ(29) DOTJ(30) DOTJ(31) \
        float ig = sigmoid_f(ai0 + ai1);                                        \
        float fg = sigmoid_f(af0 + af1);                                        \
        float gg = tanh_f(ag0 + ag1);                                           \
        float og = sigmoid_f(ao0 + ao1);                                        \
        c = fmaf(fg, c, ig * gg);                                               \
        h = og * tanh_f(c); }

    for (int tb = 0; tb < T_STEPS; tb += 4) {
        if (tb + 4 < T_STEPS) {
            n0 = ZLD(tb + 4); n1 = ZLD(tb + 5); n2 = ZLD(tb + 6); n3 = ZLD(tb + 7);
        }
        STEP(z0) STEP(z1) STEP(z2) STEP(z3)
        z0 = n0; z1 = n1; z2 = n2; z3 = n3;
    }
#undef STEP
#undef DOTJ
#undef ZLD

    // head: out = W2 @ relu(W1 @ relu(h_T)) + b2  (single wave)
    hfin[l] = h;
    __syncthreads();
    if (l < 32) {
        float s = 0.0f;
#pragma unroll
        for (int j = 0; j < HID; ++j) s += W1[l * HID + j] * fmaxf(hfin[j], 0.0f);
        hbuf[l] = fmaxf(s, 0.0f);
    }
    __syncthreads();
    if (l < 3) {
        float s = b2[l];
#pragma unroll
        for (int j = 0; j < 32; ++j) s += W2[l * 32 + j] * hbuf[j];
        out[l] = s;
    }
}

extern "C" void kernel_launch(void* const* d_in, const int* in_sizes, int n_in,
                              void* d_out, int out_size, void* d_ws, size_t ws_size,
                              hipStream_t stream) {
    const float* x   = (const float*)d_in[0];
    const float* Wih = (const float*)d_in[1];
    const float* Whh = (const float*)d_in[2];
    const float* bih = (const float*)d_in[3];
    const float* bhh = (const float*)d_in[4];
    const float* W1  = (const float*)d_in[5];
    const float* W2  = (const float*)d_in[6];
    const float* b2  = (const float*)d_in[7];
    float* out = (float*)d_out;
    float* xz2 = (float*)d_ws;   // T_STEPS * 256 floats = 64 MB (transposed layout)

    xz_kernel<<<T_STEPS / TS, 256, 0, stream>>>(x, Wih, bih, bhh, xz2);
    lstm_kernel<<<1, 64, 0, stream>>>(xz2, Whh, W1, W2, b2, out);
}